// Round 6
// baseline (351.050 us; speedup 1.0000x reference)
//
#include <hip/hip_runtime.h>
#include <hip/hip_bf16.h>

// N=8192, D_IN=128, H=64, C=40, E=262144, TAU=0.25, T=4 -> 16 steps.
constexpr int N_   = 8192;
constexpr int DIN_ = 128;
constexpr int H_   = 64;
constexpr int C_   = 40;
constexpr int STEPS_ = 16;
#define TAU_ 0.25f

typedef float f32x4 __attribute__((ext_vector_type(4)));

// ---------------- front-end (unchanged from R5) ----------------

__global__ __launch_bounds__(256) void enc_k(const float* __restrict__ xin,
    const float* __restrict__ w, const float* __restrict__ b,
    float* __restrict__ x0)
{
    int wid  = (blockIdx.x * 256 + threadIdx.x) >> 6;
    int lane = threadIdx.x & 63;
    int r0 = wid * 4;
    if (r0 >= N_) return;
    const float* xr = xin + (size_t)r0 * DIN_;
    float bv = b[lane];
    float a0 = bv, a1 = bv, a2 = bv, a3 = bv;
    for (int k = 0; k < DIN_; ++k) {
        float wv = w[k * H_ + lane];
        a0 = fmaf(xr[k],            wv, a0);
        a1 = fmaf(xr[DIN_ + k],     wv, a1);
        a2 = fmaf(xr[2 * DIN_ + k], wv, a2);
        a3 = fmaf(xr[3 * DIN_ + k], wv, a3);
    }
    float* o = x0 + (size_t)r0 * H_ + lane;
    o[0] = a0; o[H_] = a1; o[2 * H_] = a2; o[3 * H_] = a3;
}

__global__ __launch_bounds__(256) void kq_k(const float* __restrict__ x0,
    const float* __restrict__ wk, const float* __restrict__ kb,
    const float* __restrict__ wq, const float* __restrict__ qb,
    float* __restrict__ kx, float* __restrict__ qx)
{
    int wid  = (blockIdx.x * 256 + threadIdx.x) >> 6;
    int lane = threadIdx.x & 63;
    int r0 = wid * 4;
    if (r0 >= N_) return;
    const float* xr = x0 + (size_t)r0 * H_;
    float kbv = kb[lane], qbv = qb[lane];
    float ak0 = kbv, ak1 = kbv, ak2 = kbv, ak3 = kbv;
    float aq0 = qbv, aq1 = qbv, aq2 = qbv, aq3 = qbv;
    for (int k = 0; k < H_; ++k) {
        float wkv = wk[k * H_ + lane];
        float wqv = wq[k * H_ + lane];
        float x0v = xr[k], x1v = xr[H_ + k], x2v = xr[2 * H_ + k], x3v = xr[3 * H_ + k];
        ak0 = fmaf(x0v, wkv, ak0);  aq0 = fmaf(x0v, wqv, aq0);
        ak1 = fmaf(x1v, wkv, ak1);  aq1 = fmaf(x1v, wqv, aq1);
        ak2 = fmaf(x2v, wkv, ak2);  aq2 = fmaf(x2v, wqv, aq2);
        ak3 = fmaf(x3v, wkv, ak3);  aq3 = fmaf(x3v, wqv, aq3);
    }
    float* ok = kx + (size_t)r0 * H_ + lane;
    float* oq = qx + (size_t)r0 * H_ + lane;
    ok[0] = ak0; ok[H_] = ak1; ok[2 * H_] = ak2; ok[3 * H_] = ak3;
    oq[0] = aq0; oq[H_] = aq1; oq[2 * H_] = aq2; oq[3 * H_] = aq3;
}

__global__ __launch_bounds__(256) void count_k(const int2* __restrict__ edges,
    int* __restrict__ deg, int E)
{
    int e = blockIdx.x * 256 + threadIdx.x;
    if (e >= E) return;
    atomicAdd(&deg[edges[e].x], 1);
}

__global__ __launch_bounds__(256) void scan_k(const int* __restrict__ deg,
    int* __restrict__ row_ptr, int* __restrict__ row_fill)
{
    __shared__ int partial[257];
    int t = threadIdx.x;
    const int chunk = N_ / 256;
    int base = t * chunk;
    int s = 0;
    for (int i = 0; i < chunk; ++i) s += deg[base + i];
    partial[t] = s;
    __syncthreads();
    if (t == 0) {
        int run = 0;
        for (int i = 0; i < 256; ++i) { int tmp = partial[i]; partial[i] = run; run += tmp; }
        partial[256] = run;
    }
    __syncthreads();
    int run = partial[t];
    for (int i = 0; i < chunk; ++i) {
        row_ptr[base + i] = run;
        row_fill[base + i] = run;
        run += deg[base + i];
    }
    if (t == 255) row_ptr[N_] = run;
}

__global__ __launch_bounds__(256) void score_place_k(const int2* __restrict__ edges,
    const float* __restrict__ kx, const float* __restrict__ qx,
    int* __restrict__ row_fill, int* __restrict__ csr_v, float* __restrict__ csr_w, int E)
{
    int t  = blockIdx.x * 256 + threadIdx.x;
    int eg = t >> 4;
    int sl = t & 15;
    if (eg >= E) return;
    int2 uv = edges[eg];
    float4 a = ((const float4*)(kx + (size_t)uv.x * H_))[sl];
    float4 b = ((const float4*)(qx + (size_t)uv.y * H_))[sl];
    float d = a.x * b.x + a.y * b.y + a.z * b.z + a.w * b.w;
    d += __shfl_xor(d, 1);
    d += __shfl_xor(d, 2);
    d += __shfl_xor(d, 4);
    d += __shfl_xor(d, 8);
    if (sl == 0) {
        float w = expf(d * (1.0f / (float)H_));
        int pos = atomicAdd(&row_fill[uv.x], 1);
        csr_v[pos] = uv.y;
        csr_w[pos] = w;
    }
}

__global__ __launch_bounds__(256) void dedup_k(const int* __restrict__ row_ptr,
    const int* __restrict__ csr_v, const float* __restrict__ csr_w,
    int2* __restrict__ vw)
{
    __shared__ unsigned int bm[4][256];   // 8192 bits per wave
    int wv   = threadIdx.x >> 6;
    int lane = threadIdx.x & 63;
    int row  = blockIdx.x * 4 + wv;
    unsigned int* b = bm[wv];
    for (int i = lane; i < 256; i += 64) b[i] = 0;
    __syncthreads();
    int p0 = row_ptr[row], p1 = row_ptr[row + 1];
    float wsum = 0.f;
    for (int p = p0 + lane; p < p1; p += 64) {
        int v = csr_v[p];
        unsigned int m = 1u << (v & 31);
        unsigned int old = atomicOr(&b[v >> 5], m);
        float w = (old & m) ? 0.0f : csr_w[p];
        vw[p] = make_int2(v, __float_as_int(w));
        wsum += w;
    }
    #pragma unroll
    for (int off = 1; off < 64; off <<= 1) wsum += __shfl_xor(wsum, off);
    if (p0 == p1) return;                  // empty row
    float scale = TAU_ / wsum;
    for (int p = p0 + lane; p < p1; p += 64) {
        int2 e = vw[p];
        e.y = __float_as_int(__int_as_float(e.y) * scale);
        vw[p] = e;
    }
}

// ---------------- device-coherent (MALL-scope) load/store helpers ----------
// sc0 sc1 on global ops = bypass L1+L2, coherent at Infinity Cache across
// XCDs. Batched issue, single s_waitcnt -> up to 8 gathers in flight/wave.

__device__ __forceinline__ void dev_load2(const float* pa, const float* pb,
    f32x4& a, f32x4& b)
{
    asm volatile(
        "global_load_dwordx4 %0, %2, off sc0 sc1\n\t"
        "global_load_dwordx4 %1, %3, off sc0 sc1\n\t"
        "s_waitcnt vmcnt(0)"
        : "=&v"(a), "=&v"(b)
        : "v"(pa), "v"(pb)
        : "memory");
}

__device__ __forceinline__ void dev_load4(const float* p0, const float* p1,
    const float* p2, const float* p3,
    f32x4& g0, f32x4& g1, f32x4& g2, f32x4& g3)
{
    asm volatile(
        "global_load_dwordx4 %0, %4, off sc0 sc1\n\t"
        "global_load_dwordx4 %1, %5, off sc0 sc1\n\t"
        "global_load_dwordx4 %2, %6, off sc0 sc1\n\t"
        "global_load_dwordx4 %3, %7, off sc0 sc1\n\t"
        "s_waitcnt vmcnt(0)"
        : "=&v"(g0), "=&v"(g1), "=&v"(g2), "=&v"(g3)
        : "v"(p0), "v"(p1), "v"(p2), "v"(p3)
        : "memory");
}

__device__ __forceinline__ void dev_load8(
    const float* p0, const float* p1, const float* p2, const float* p3,
    const float* p4, const float* p5, const float* p6, const float* p7,
    f32x4& g0, f32x4& g1, f32x4& g2, f32x4& g3,
    f32x4& g4, f32x4& g5, f32x4& g6, f32x4& g7)
{
    asm volatile(
        "global_load_dwordx4 %0, %8, off sc0 sc1\n\t"
        "global_load_dwordx4 %1, %9, off sc0 sc1\n\t"
        "global_load_dwordx4 %2, %10, off sc0 sc1\n\t"
        "global_load_dwordx4 %3, %11, off sc0 sc1\n\t"
        "global_load_dwordx4 %4, %12, off sc0 sc1\n\t"
        "global_load_dwordx4 %5, %13, off sc0 sc1\n\t"
        "global_load_dwordx4 %6, %14, off sc0 sc1\n\t"
        "global_load_dwordx4 %7, %15, off sc0 sc1\n\t"
        "s_waitcnt vmcnt(0)"
        : "=&v"(g0), "=&v"(g1), "=&v"(g2), "=&v"(g3),
          "=&v"(g4), "=&v"(g5), "=&v"(g6), "=&v"(g7)
        : "v"(p0), "v"(p1), "v"(p2), "v"(p3),
          "v"(p4), "v"(p5), "v"(p6), "v"(p7)
        : "memory");
}

__device__ __forceinline__ void dev_store(float* p, f32x4 v)
{
    asm volatile("global_store_dwordx4 %0, %1, off sc0 sc1"
                 :: "v"(p), "v"(v) : "memory");
}

#define FMA4(acc, w, g) do { \
    acc[0] = fmaf((w), (g)[0], acc[0]); acc[1] = fmaf((w), (g)[1], acc[1]); \
    acc[2] = fmaf((w), (g)[2], acc[2]); acc[3] = fmaf((w), (g)[3], acc[3]); } while (0)

#define RED4(a) do { \
    a[0] += __shfl_xor(a[0], 16); a[1] += __shfl_xor(a[1], 16); \
    a[2] += __shfl_xor(a[2], 16); a[3] += __shfl_xor(a[3], 16); \
    a[0] += __shfl_xor(a[0], 32); a[1] += __shfl_xor(a[1], 32); \
    a[2] += __shfl_xor(a[2], 32); a[3] += __shfl_xor(a[3], 32); } while (0)

// ---------------- fused 16-step propagation + decode ----------------
// 256 blocks x 1024 threads; launch_bounds(1024,4) caps VGPR at 128 -> exactly
// 1 block/CU, 256 blocks <= 256 CUs -> all co-resident -> software barrier
// safe. x traffic (gathers + intermediate stores) is MALL-coherent via sc0 sc1;
// vw/row_ptr/dw stay L2-cached (read-only during this kernel). Barrier needs
// NO cache flush: vmcnt drain + relaxed agent-scope arrival counter.
__global__ __launch_bounds__(1024, 4) void steps_k(
    float* __restrict__ x0buf, float* __restrict__ xbbuf,
    const int* __restrict__ row_ptr, const int2* __restrict__ vw,
    const float* __restrict__ dw, const float* __restrict__ db,
    float* __restrict__ out, int* __restrict__ bar)
{
    const int NBLK = 256;
    int wid  = (blockIdx.x << 4) + (threadIdx.x >> 6);   // 0..4095
    int lane = threadIdx.x & 63;
    int grp  = lane >> 4;
    int col4 = lane & 15;
    int rA = wid * 2, rB = rA + 1;
    int pA0 = row_ptr[rA];
    int pAe = row_ptr[rA + 1];                            // == start of rB
    int pBe = row_ptr[rB + 1];

    float* xa = x0buf;
    float* xo = xbbuf;

    #define PTRX(e) (xa + ((size_t)(e).x << 6) + (col4 << 2))
    #define WVAL(e) __int_as_float((e).y)

    for (int s = 0; s < STEPS_; ++s) {
        // diagonal term rows (written by other blocks last step -> sc0 sc1)
        f32x4 xrA, xrB;
        dev_load2(xa + ((size_t)rA << 6) + (col4 << 2),
                  xa + ((size_t)rB << 6) + (col4 << 2), xrA, xrB);

        f32x4 aA = {0.f, 0.f, 0.f, 0.f}, aB = {0.f, 0.f, 0.f, 0.f};
        int pA = pA0, pB = pAe;

        // merged dual-row main loop: 8 gathers in flight per batch
        while (pA < pAe && pB < pBe) {
            int iA = pA + grp, iB = pB + grp;
            int2 eA0 = (iA      < pAe) ? vw[iA]      : make_int2(0, 0);
            int2 eA1 = (iA + 4  < pAe) ? vw[iA + 4]  : make_int2(0, 0);
            int2 eA2 = (iA + 8  < pAe) ? vw[iA + 8]  : make_int2(0, 0);
            int2 eA3 = (iA + 12 < pAe) ? vw[iA + 12] : make_int2(0, 0);
            int2 eB0 = (iB      < pBe) ? vw[iB]      : make_int2(0, 0);
            int2 eB1 = (iB + 4  < pBe) ? vw[iB + 4]  : make_int2(0, 0);
            int2 eB2 = (iB + 8  < pBe) ? vw[iB + 8]  : make_int2(0, 0);
            int2 eB3 = (iB + 12 < pBe) ? vw[iB + 12] : make_int2(0, 0);
            f32x4 gA0, gA1, gA2, gA3, gB0, gB1, gB2, gB3;
            dev_load8(PTRX(eA0), PTRX(eA1), PTRX(eA2), PTRX(eA3),
                      PTRX(eB0), PTRX(eB1), PTRX(eB2), PTRX(eB3),
                      gA0, gA1, gA2, gA3, gB0, gB1, gB2, gB3);
            FMA4(aA, WVAL(eA0), gA0); FMA4(aA, WVAL(eA1), gA1);
            FMA4(aA, WVAL(eA2), gA2); FMA4(aA, WVAL(eA3), gA3);
            FMA4(aB, WVAL(eB0), gB0); FMA4(aB, WVAL(eB1), gB1);
            FMA4(aB, WVAL(eB2), gB2); FMA4(aB, WVAL(eB3), gB3);
            pA += 16; pB += 16;
        }
        while (pA < pAe) {            // drain row A
            int iA = pA + grp;
            int2 e0 = (iA      < pAe) ? vw[iA]      : make_int2(0, 0);
            int2 e1 = (iA + 4  < pAe) ? vw[iA + 4]  : make_int2(0, 0);
            int2 e2 = (iA + 8  < pAe) ? vw[iA + 8]  : make_int2(0, 0);
            int2 e3 = (iA + 12 < pAe) ? vw[iA + 12] : make_int2(0, 0);
            f32x4 g0, g1, g2, g3;
            dev_load4(PTRX(e0), PTRX(e1), PTRX(e2), PTRX(e3), g0, g1, g2, g3);
            FMA4(aA, WVAL(e0), g0); FMA4(aA, WVAL(e1), g1);
            FMA4(aA, WVAL(e2), g2); FMA4(aA, WVAL(e3), g3);
            pA += 16;
        }
        while (pB < pBe) {            // drain row B
            int iB = pB + grp;
            int2 e0 = (iB      < pBe) ? vw[iB]      : make_int2(0, 0);
            int2 e1 = (iB + 4  < pBe) ? vw[iB + 4]  : make_int2(0, 0);
            int2 e2 = (iB + 8  < pBe) ? vw[iB + 8]  : make_int2(0, 0);
            int2 e3 = (iB + 12 < pBe) ? vw[iB + 12] : make_int2(0, 0);
            f32x4 g0, g1, g2, g3;
            dev_load4(PTRX(e0), PTRX(e1), PTRX(e2), PTRX(e3), g0, g1, g2, g3);
            FMA4(aB, WVAL(e0), g0); FMA4(aB, WVAL(e1), g1);
            FMA4(aB, WVAL(e2), g2); FMA4(aB, WVAL(e3), g3);
            pB += 16;
        }

        RED4(aA); RED4(aB);
        bool last = (s == STEPS_ - 1);
        if (grp == 0) {
            f32x4 r;
            r[0] = fmaf(1.0f - TAU_, xrA[0], aA[0]);
            r[1] = fmaf(1.0f - TAU_, xrA[1], aA[1]);
            r[2] = fmaf(1.0f - TAU_, xrA[2], aA[2]);
            r[3] = fmaf(1.0f - TAU_, xrA[3], aA[3]);
            float* pdst = xo + ((size_t)rA << 6) + (col4 << 2);
            if (last) *(f32x4*)pdst = r; else dev_store(pdst, r);
            r[0] = fmaf(1.0f - TAU_, xrB[0], aB[0]);
            r[1] = fmaf(1.0f - TAU_, xrB[1], aB[1]);
            r[2] = fmaf(1.0f - TAU_, xrB[2], aB[2]);
            r[3] = fmaf(1.0f - TAU_, xrB[3], aB[3]);
            pdst = xo + ((size_t)rB << 6) + (col4 << 2);
            if (last) *(f32x4*)pdst = r; else dev_store(pdst, r);
        }
        { float* t = xa; xa = xo; xo = t; }

        if (!last) {
            asm volatile("s_waitcnt vmcnt(0)" ::: "memory");  // drain sc1 stores
            __syncthreads();
            if (threadIdx.x == 0) {
                __hip_atomic_fetch_add(bar, 1, __ATOMIC_RELAXED, __HIP_MEMORY_SCOPE_AGENT);
                int target = (s + 1) * NBLK;
                while (__hip_atomic_load(bar, __ATOMIC_RELAXED, __HIP_MEMORY_SCOPE_AGENT) < target)
                    __builtin_amdgcn_s_sleep(2);
            }
            __syncthreads();
        }
    }
    #undef PTRX
    #undef WVAL

    // decode own rows (written by this wave with normal stores -> L1-coherent)
    if (lane < C_) {
        const float* xr = xa + ((size_t)rA << 6);
        float a = db[lane];
        for (int k = 0; k < H_; ++k) a = fmaf(xr[k], dw[k * C_ + lane], a);
        out[(size_t)rA * C_ + lane] = a;
        xr = xa + ((size_t)rB << 6);
        a = db[lane];
        for (int k = 0; k < H_; ++k) a = fmaf(xr[k], dw[k * C_ + lane], a);
        out[(size_t)rB * C_ + lane] = a;
    }
}

extern "C" void kernel_launch(void* const* d_in, const int* in_sizes, int n_in,
                              void* d_out, int out_size, void* d_ws, size_t ws_size,
                              hipStream_t stream)
{
    const float* x_in  = (const float*)d_in[0];
    const float* enc_w = (const float*)d_in[1];
    const float* enc_b = (const float*)d_in[2];
    const float* wk_w  = (const float*)d_in[3];
    const float* wk_b  = (const float*)d_in[4];
    const float* wq_w  = (const float*)d_in[5];
    const float* wq_b  = (const float*)d_in[6];
    const float* dec_w = (const float*)d_in[7];
    const float* dec_b = (const float*)d_in[8];
    const int2*  edges = (const int2*)d_in[9];
    const int E = in_sizes[9] / 2;   // 262144
    float* out = (float*)d_out;

    char* ws = (char*)d_ws;
    float* x0       = (float*)(ws + 0);                           // 2 MB
    float* xb       = (float*)(ws + (2u << 20));                  // 2 MB
    float* kx       = (float*)(ws + (4u << 20));                  // 2 MB
    float* qx       = (float*)(ws + (6u << 20));                  // 2 MB
    int*   csr_v    = (int*)  (ws + (8u << 20));                  // 1 MB
    float* csr_w    = (float*)(ws + (9u << 20));                  // 1 MB
    int2*  vw       = (int2*) (ws + (10u << 20));                 // 2 MB
    int*   deg      = (int*)  (ws + (12u << 20));                 // 32 KB
    int*   bar      = (int*)  (ws + (12u << 20) + (32u << 10));   // 4 B
    int*   row_ptr  = (int*)  (ws + (12u << 20) + (64u << 10));   // 32 KB + 4
    int*   row_fill = (int*)  (ws + (12u << 20) + (128u << 10));  // 32 KB

    // zero deg + barrier counter (contiguous range)
    hipMemsetAsync(deg, 0, (32u << 10) + 64, stream);

    enc_k<<<N_ / 16, 256, 0, stream>>>(x_in, enc_w, enc_b, x0);
    kq_k <<<N_ / 16, 256, 0, stream>>>(x0, wk_w, wk_b, wq_w, wq_b, kx, qx);
    count_k<<<(E + 255) / 256, 256, 0, stream>>>(edges, deg, E);
    scan_k<<<1, 256, 0, stream>>>(deg, row_ptr, row_fill);
    score_place_k<<<(E * 16 + 255) / 256, 256, 0, stream>>>(edges, kx, qx, row_fill, csr_v, csr_w, E);
    dedup_k<<<N_ / 4, 256, 0, stream>>>(row_ptr, csr_v, csr_w, vw);

    steps_k<<<256, 1024, 0, stream>>>(x0, xb, row_ptr, vw, dec_w, dec_b, out, bar);
}

// Round 7
// 214.582 us; speedup vs baseline: 1.6360x; 1.6360x over previous
//
#include <hip/hip_runtime.h>
#include <hip/hip_bf16.h>

// N=8192, D_IN=128, H=64, C=40, E=262144, TAU=0.25, T=4 -> 16 steps.
constexpr int N_   = 8192;
constexpr int DIN_ = 128;
constexpr int H_   = 64;
constexpr int C_   = 40;
constexpr int STEPS_ = 16;
#define TAU_ 0.25f

typedef float f32x4 __attribute__((ext_vector_type(4)));

// ---------------- fused front-end: enc + kq + z0 = x0 @ dec_w ---------------
// Decode-first identity: out = U^16(x0) @ Wd + b == U^16(x0 @ Wd) + b.
// Wave = 4 rows; lane = column. x0 lives only in an LDS tile (wave-local,
// no barrier needed: same wave writes then reads its 4 rows).
__global__ __launch_bounds__(256) void front_k(const float* __restrict__ xin,
    const float* __restrict__ ew, const float* __restrict__ eb,
    const float* __restrict__ wk, const float* __restrict__ kb,
    const float* __restrict__ wq, const float* __restrict__ qb,
    const float* __restrict__ dw,
    float* __restrict__ kx, float* __restrict__ qx, float* __restrict__ z0)
{
    __shared__ float xs[16][64];                 // 4 waves x 4 rows
    int wloc = threadIdx.x >> 6;                 // wave in block
    int lane = threadIdx.x & 63;
    int r0   = (blockIdx.x * 4 + wloc) * 4;      // first of this wave's 4 rows

    // ---- enc: x0 rows r0..r0+3 ----
    const float* xr = xin + (size_t)r0 * DIN_;
    float bv = eb[lane];
    float a0 = bv, a1 = bv, a2 = bv, a3 = bv;
    for (int k = 0; k < DIN_; ++k) {
        float wv = ew[k * H_ + lane];
        a0 = fmaf(xr[k],            wv, a0);
        a1 = fmaf(xr[DIN_ + k],     wv, a1);
        a2 = fmaf(xr[2 * DIN_ + k], wv, a2);
        a3 = fmaf(xr[3 * DIN_ + k], wv, a3);
    }
    float* xls = &xs[wloc * 4][0];
    xls[lane] = a0; xls[64 + lane] = a1; xls[128 + lane] = a2; xls[192 + lane] = a3;
    // wave-synchronous LDS RAW: compiler inserts lgkmcnt wait; no barrier.

    // ---- kq: kx/qx rows ----
    float kbv = kb[lane], qbv = qb[lane];
    float ak0 = kbv, ak1 = kbv, ak2 = kbv, ak3 = kbv;
    float aq0 = qbv, aq1 = qbv, aq2 = qbv, aq3 = qbv;
    for (int k = 0; k < H_; ++k) {
        float wkv = wk[k * H_ + lane];
        float wqv = wq[k * H_ + lane];
        float x0v = xls[k], x1v = xls[64 + k], x2v = xls[128 + k], x3v = xls[192 + k];
        ak0 = fmaf(x0v, wkv, ak0);  aq0 = fmaf(x0v, wqv, aq0);
        ak1 = fmaf(x1v, wkv, ak1);  aq1 = fmaf(x1v, wqv, aq1);
        ak2 = fmaf(x2v, wkv, ak2);  aq2 = fmaf(x2v, wqv, aq2);
        ak3 = fmaf(x3v, wkv, ak3);  aq3 = fmaf(x3v, wqv, aq3);
    }
    float* ok = kx + (size_t)r0 * H_ + lane;
    float* oq = qx + (size_t)r0 * H_ + lane;
    ok[0] = ak0; ok[H_] = ak1; ok[2 * H_] = ak2; ok[3 * H_] = ak3;
    oq[0] = aq0; oq[H_] = aq1; oq[2 * H_] = aq2; oq[3 * H_] = aq3;

    // ---- z0 = x0 @ dec_w (no bias; bias added in last step) ----
    if (lane < C_) {
        float z0a = 0.f, z1a = 0.f, z2a = 0.f, z3a = 0.f;
        for (int k = 0; k < H_; ++k) {
            float dv = dw[k * C_ + lane];
            z0a = fmaf(xls[k],       dv, z0a);
            z1a = fmaf(xls[64 + k],  dv, z1a);
            z2a = fmaf(xls[128 + k], dv, z2a);
            z3a = fmaf(xls[192 + k], dv, z3a);
        }
        z0[(size_t)r0 * C_ + lane]       = z0a;
        z0[(size_t)(r0 + 1) * C_ + lane] = z1a;
        z0[(size_t)(r0 + 2) * C_ + lane] = z2a;
        z0[(size_t)(r0 + 3) * C_ + lane] = z3a;
    }
}

// ---------------- edge pipeline (unchanged from R5) ----------------

__global__ __launch_bounds__(256) void count_k(const int2* __restrict__ edges,
    int* __restrict__ deg, int E)
{
    int e = blockIdx.x * 256 + threadIdx.x;
    if (e >= E) return;
    atomicAdd(&deg[edges[e].x], 1);
}

__global__ __launch_bounds__(256) void scan_k(const int* __restrict__ deg,
    int* __restrict__ row_ptr, int* __restrict__ row_fill)
{
    __shared__ int partial[257];
    int t = threadIdx.x;
    const int chunk = N_ / 256;
    int base = t * chunk;
    int s = 0;
    for (int i = 0; i < chunk; ++i) s += deg[base + i];
    partial[t] = s;
    __syncthreads();
    if (t == 0) {
        int run = 0;
        for (int i = 0; i < 256; ++i) { int tmp = partial[i]; partial[i] = run; run += tmp; }
        partial[256] = run;
    }
    __syncthreads();
    int run = partial[t];
    for (int i = 0; i < chunk; ++i) {
        row_ptr[base + i] = run;
        row_fill[base + i] = run;
        run += deg[base + i];
    }
    if (t == 255) row_ptr[N_] = run;
}

__global__ __launch_bounds__(256) void score_place_k(const int2* __restrict__ edges,
    const float* __restrict__ kx, const float* __restrict__ qx,
    int* __restrict__ row_fill, int* __restrict__ csr_v, float* __restrict__ csr_w, int E)
{
    int t  = blockIdx.x * 256 + threadIdx.x;
    int eg = t >> 4;
    int sl = t & 15;
    if (eg >= E) return;
    int2 uv = edges[eg];
    float4 a = ((const float4*)(kx + (size_t)uv.x * H_))[sl];
    float4 b = ((const float4*)(qx + (size_t)uv.y * H_))[sl];
    float d = a.x * b.x + a.y * b.y + a.z * b.z + a.w * b.w;
    d += __shfl_xor(d, 1);
    d += __shfl_xor(d, 2);
    d += __shfl_xor(d, 4);
    d += __shfl_xor(d, 8);
    if (sl == 0) {
        float w = expf(d * (1.0f / (float)H_));
        int pos = atomicAdd(&row_fill[uv.x], 1);
        csr_v[pos] = uv.y;
        csr_w[pos] = w;
    }
}

__global__ __launch_bounds__(256) void dedup_k(const int* __restrict__ row_ptr,
    const int* __restrict__ csr_v, const float* __restrict__ csr_w,
    int2* __restrict__ vw)
{
    __shared__ unsigned int bm[4][256];   // 8192 bits per wave
    int wv   = threadIdx.x >> 6;
    int lane = threadIdx.x & 63;
    int row  = blockIdx.x * 4 + wv;
    unsigned int* b = bm[wv];
    for (int i = lane; i < 256; i += 64) b[i] = 0;
    __syncthreads();
    int p0 = row_ptr[row], p1 = row_ptr[row + 1];
    float wsum = 0.f;
    for (int p = p0 + lane; p < p1; p += 64) {
        int v = csr_v[p];
        unsigned int m = 1u << (v & 31);
        unsigned int old = atomicOr(&b[v >> 5], m);
        float w = (old & m) ? 0.0f : csr_w[p];
        vw[p] = make_int2(v, __float_as_int(w));
        wsum += w;
    }
    #pragma unroll
    for (int off = 1; off < 64; off <<= 1) wsum += __shfl_xor(wsum, off);
    if (p0 == p1) return;                  // empty row
    float scale = TAU_ / wsum;
    for (int p = p0 + lane; p < p1; p += 64) {
        int2 e = vw[p];
        e.y = __float_as_int(__int_as_float(e.y) * scale);
        vw[p] = e;
    }
}

// ---------------- propagation step over z (N x 40, row stride 40 floats) ----
// Wave = row. Lane L: edge-group grp=L>>4, float4-column c=L&15 (c<10 valid;
// c>=10 lanes duplicate column 9 — harmless, discarded at store; shfl_xor
// 16/32 reduce never mixes different c). 4 dwordx4 gathers per 16-edge chunk.
// LAST step adds dec_b and writes the external output.
template <bool LAST>
__global__ __launch_bounds__(256) void stepz_k(const float* __restrict__ zin,
    float* __restrict__ zout, const int* __restrict__ row_ptr,
    const int2* __restrict__ vw, const float* __restrict__ db)
{
    int row  = (blockIdx.x * 256 + threadIdx.x) >> 6;
    int lane = threadIdx.x & 63;
    int grp  = lane >> 4;
    int col4 = lane & 15;
    int c9   = (col4 < 10) ? col4 : 9;           // clamped gather column
    int p0 = row_ptr[row], p1 = row_ptr[row + 1];
    f32x4 acc = {0.f, 0.f, 0.f, 0.f};
    for (int base = p0; base < p1; base += 16) {
        int i0 = base + grp, i1 = i0 + 4, i2 = i0 + 8, i3 = i0 + 12;
        int2 e0 = (i0 < p1) ? vw[i0] : make_int2(0, 0);
        int2 e1 = (i1 < p1) ? vw[i1] : make_int2(0, 0);
        int2 e2 = (i2 < p1) ? vw[i2] : make_int2(0, 0);
        int2 e3 = (i3 < p1) ? vw[i3] : make_int2(0, 0);
        f32x4 g0 = *(const f32x4*)(zin + (size_t)e0.x * C_ + (c9 << 2));
        f32x4 g1 = *(const f32x4*)(zin + (size_t)e1.x * C_ + (c9 << 2));
        f32x4 g2 = *(const f32x4*)(zin + (size_t)e2.x * C_ + (c9 << 2));
        f32x4 g3 = *(const f32x4*)(zin + (size_t)e3.x * C_ + (c9 << 2));
        float w0 = __int_as_float(e0.y), w1 = __int_as_float(e1.y);
        float w2 = __int_as_float(e2.y), w3 = __int_as_float(e3.y);
        acc[0] = fmaf(w0, g0[0], acc[0]); acc[1] = fmaf(w0, g0[1], acc[1]);
        acc[2] = fmaf(w0, g0[2], acc[2]); acc[3] = fmaf(w0, g0[3], acc[3]);
        acc[0] = fmaf(w1, g1[0], acc[0]); acc[1] = fmaf(w1, g1[1], acc[1]);
        acc[2] = fmaf(w1, g1[2], acc[2]); acc[3] = fmaf(w1, g1[3], acc[3]);
        acc[0] = fmaf(w2, g2[0], acc[0]); acc[1] = fmaf(w2, g2[1], acc[1]);
        acc[2] = fmaf(w2, g2[2], acc[2]); acc[3] = fmaf(w2, g2[3], acc[3]);
        acc[0] = fmaf(w3, g3[0], acc[0]); acc[1] = fmaf(w3, g3[1], acc[1]);
        acc[2] = fmaf(w3, g3[2], acc[2]); acc[3] = fmaf(w3, g3[3], acc[3]);
    }
    acc[0] += __shfl_xor(acc[0], 16); acc[1] += __shfl_xor(acc[1], 16);
    acc[2] += __shfl_xor(acc[2], 16); acc[3] += __shfl_xor(acc[3], 16);
    acc[0] += __shfl_xor(acc[0], 32); acc[1] += __shfl_xor(acc[1], 32);
    acc[2] += __shfl_xor(acc[2], 32); acc[3] += __shfl_xor(acc[3], 32);
    if (grp == 0 && col4 < 10) {
        f32x4 xr = *(const f32x4*)(zin + (size_t)row * C_ + (col4 << 2));
        f32x4 r;
        r[0] = fmaf(1.0f - TAU_, xr[0], acc[0]);
        r[1] = fmaf(1.0f - TAU_, xr[1], acc[1]);
        r[2] = fmaf(1.0f - TAU_, xr[2], acc[2]);
        r[3] = fmaf(1.0f - TAU_, xr[3], acc[3]);
        if (LAST) {
            f32x4 bb = *(const f32x4*)(db + (col4 << 2));
            r[0] += bb[0]; r[1] += bb[1]; r[2] += bb[2]; r[3] += bb[3];
        }
        *(f32x4*)(zout + (size_t)row * C_ + (col4 << 2)) = r;
    }
}

extern "C" void kernel_launch(void* const* d_in, const int* in_sizes, int n_in,
                              void* d_out, int out_size, void* d_ws, size_t ws_size,
                              hipStream_t stream)
{
    const float* x_in  = (const float*)d_in[0];
    const float* enc_w = (const float*)d_in[1];
    const float* enc_b = (const float*)d_in[2];
    const float* wk_w  = (const float*)d_in[3];
    const float* wk_b  = (const float*)d_in[4];
    const float* wq_w  = (const float*)d_in[5];
    const float* wq_b  = (const float*)d_in[6];
    const float* dec_w = (const float*)d_in[7];
    const float* dec_b = (const float*)d_in[8];
    const int2*  edges = (const int2*)d_in[9];
    const int E = in_sizes[9] / 2;   // 262144
    float* out = (float*)d_out;

    char* ws = (char*)d_ws;
    float* za       = (float*)(ws + 0);                           // 1.25 MB + pad
    float* zb       = (float*)(ws + (2u << 20));                  // 1.25 MB + pad
    float* kx       = (float*)(ws + (4u << 20));                  // 2 MB
    float* qx       = (float*)(ws + (6u << 20));                  // 2 MB
    int*   csr_v    = (int*)  (ws + (8u << 20));                  // 1 MB
    float* csr_w    = (float*)(ws + (9u << 20));                  // 1 MB
    int2*  vw       = (int2*) (ws + (10u << 20));                 // 2 MB
    int*   deg      = (int*)  (ws + (12u << 20));                 // 32 KB
    int*   row_ptr  = (int*)  (ws + (12u << 20) + (64u << 10));   // 32 KB + 4
    int*   row_fill = (int*)  (ws + (12u << 20) + (128u << 10));  // 32 KB

    hipMemsetAsync(deg, 0, N_ * sizeof(int), stream);

    front_k<<<N_ / 16, 256, 0, stream>>>(x_in, enc_w, enc_b, wk_w, wk_b,
                                         wq_w, wq_b, dec_w, kx, qx, za);
    count_k<<<(E + 255) / 256, 256, 0, stream>>>(edges, deg, E);
    scan_k<<<1, 256, 0, stream>>>(deg, row_ptr, row_fill);
    score_place_k<<<(E * 16 + 255) / 256, 256, 0, stream>>>(edges, kx, qx, row_fill, csr_v, csr_w, E);
    dedup_k<<<N_ / 4, 256, 0, stream>>>(row_ptr, csr_v, csr_w, vw);

    // 15 ping-pong steps in z-space + final step fused with bias -> d_out
    float* zi = za;
    for (int s = 0; s < STEPS_ - 1; ++s) {
        stepz_k<false><<<N_ / 4, 256, 0, stream>>>(zi, (zi == za) ? zb : za,
                                                   row_ptr, vw, dec_b);
        zi = (zi == za) ? zb : za;
    }
    stepz_k<true><<<N_ / 4, 256, 0, stream>>>(zi, out, row_ptr, vw, dec_b);
}